// Round 1
// baseline (4144.978 us; speedup 1.0000x reference)
//
#include <hip/hip_runtime.h>

// ---------------------------------------------------------------------------
// 2-layer GCN forward on MI355X.
// deg -> dinv -> per-edge norm -> GEMM1 (f32 tiled) -> atomic scatter-agg(128)
// -> relu+bias+selfloop -> GEMM2 -> atomic scatter-agg(40) -> +self +bias.
// Workspace layout (floats): deg[n], dinv[n], norm[E], idx[2E] (int), flag[1],
// H1[n*128], A1[n*128]; H2 reuses H1 after relu.
// ---------------------------------------------------------------------------

__global__ void k_detect(const int* __restrict__ e32, int* __restrict__ flag) {
    // sample odd int32 slots of the first 256 index pairs; if any nonzero,
    // storage is int32; if all zero, it's int64 (little-endian high words).
    int t = threadIdx.x;
    if (e32[2 * t + 1] != 0) atomicOr(flag, 1);
}

__global__ void k_convert(const void* __restrict__ e_raw, int* __restrict__ idx,
                          const int* __restrict__ flag, int twoE) {
    int i = blockIdx.x * blockDim.x + threadIdx.x;
    if (i >= twoE) return;
    if (*flag == 0)
        idx[i] = (int)((const long long*)e_raw)[i];   // int64 storage
    else
        idx[i] = ((const int*)e_raw)[i];              // int32 storage
}

__global__ void k_count(const int* __restrict__ dst, float* __restrict__ deg, int E) {
    int j = blockIdx.x * blockDim.x + threadIdx.x;
    if (j < E) atomicAdd(&deg[dst[j]], 1.0f);
}

__global__ void k_dinv(const float* __restrict__ deg, float* __restrict__ dinv, int n) {
    int i = blockIdx.x * blockDim.x + threadIdx.x;
    if (i < n) dinv[i] = rsqrtf(deg[i] + 1.0f);   // +1 = self-loop
}

__global__ void k_norm(const int* __restrict__ src, const int* __restrict__ dst,
                       const float* __restrict__ dinv, float* __restrict__ w, int E) {
    int j = blockIdx.x * blockDim.x + threadIdx.x;
    if (j < E) w[j] = dinv[src[j]] * dinv[dst[j]];
}

// ---- GEMM1: [n,128] @ [128,128] -> [n,128].  128-row tile, 8x8 micro-tile,
// K staged in 32-chunks (xT transposed w/ pad-130, W row-major). 32.6 KB LDS.
__global__ __launch_bounds__(256) void k_gemm1(const float* __restrict__ X,
                                               const float* __restrict__ W,
                                               float* __restrict__ H, int n) {
    __shared__ float xT[32][130];
    __shared__ float wsh[32][128];
    const int tid = threadIdx.x;
    const int row0 = blockIdx.x * 128;
    const int tr = tid & 15;    // rows tr + 16*m
    const int tc = tid >> 4;    // cols tc*8 .. +7
    float acc[8][8];
#pragma unroll
    for (int m = 0; m < 8; m++)
#pragma unroll
        for (int c = 0; c < 8; c++) acc[m][c] = 0.f;

    for (int k0 = 0; k0 < 128; k0 += 32) {
#pragma unroll
        for (int it = 0; it < 4; it++) {            // stage X chunk, transposed
            int i = tid + it * 256;                 // 0..1023
            int r = i >> 3;
            int c4 = (i & 7) << 2;
            int gr = row0 + r;
            float4 v = make_float4(0.f, 0.f, 0.f, 0.f);
            if (gr < n) v = *(const float4*)(X + (size_t)gr * 128 + k0 + c4);
            xT[c4 + 0][r] = v.x; xT[c4 + 1][r] = v.y;
            xT[c4 + 2][r] = v.z; xT[c4 + 3][r] = v.w;
        }
#pragma unroll
        for (int it = 0; it < 4; it++) {            // stage W chunk
            int i = tid + it * 256;
            int kk = i >> 5;
            int c4 = (i & 31) << 2;
            *(float4*)&wsh[kk][c4] = *(const float4*)(W + (size_t)(k0 + kk) * 128 + c4);
        }
        __syncthreads();
#pragma unroll
        for (int k = 0; k < 32; k++) {
            float a[8];
#pragma unroll
            for (int m = 0; m < 8; m++) a[m] = xT[k][tr + 16 * m];
            float4 b0 = *(float4*)&wsh[k][tc * 8];
            float4 b1 = *(float4*)&wsh[k][tc * 8 + 4];
            float b[8] = {b0.x, b0.y, b0.z, b0.w, b1.x, b1.y, b1.z, b1.w};
#pragma unroll
            for (int m = 0; m < 8; m++)
#pragma unroll
                for (int c = 0; c < 8; c++) acc[m][c] = fmaf(a[m], b[c], acc[m][c]);
        }
        __syncthreads();
    }
#pragma unroll
    for (int m = 0; m < 8; m++) {
        int gr = row0 + tr + 16 * m;
        if (gr < n) {
            *(float4*)(H + (size_t)gr * 128 + tc * 8) =
                make_float4(acc[m][0], acc[m][1], acc[m][2], acc[m][3]);
            *(float4*)(H + (size_t)gr * 128 + tc * 8 + 4) =
                make_float4(acc[m][4], acc[m][5], acc[m][6], acc[m][7]);
        }
    }
}

// ---- GEMM2: [n,128] @ [128,40] -> [n,40]. 256-row tile, 8x5 micro-tile.
__global__ __launch_bounds__(256) void k_gemm2(const float* __restrict__ Hh,
                                               const float* __restrict__ W2,
                                               float* __restrict__ H2, int n) {
    __shared__ float xT[32][258];
    __shared__ float wsh[32][40];
    const int tid = threadIdx.x;
    const int row0 = blockIdx.x * 256;
    const int tr = tid & 31;    // rows tr + 32*m
    const int tc = tid >> 5;    // 0..7, cols tc*5 .. +4
    float acc[8][5];
#pragma unroll
    for (int m = 0; m < 8; m++)
#pragma unroll
        for (int c = 0; c < 5; c++) acc[m][c] = 0.f;

    for (int k0 = 0; k0 < 128; k0 += 32) {
#pragma unroll
        for (int it = 0; it < 8; it++) {            // stage Hh chunk transposed
            int i = tid + it * 256;                 // 0..2047
            int r = i >> 3;
            int c4 = (i & 7) << 2;
            int gr = row0 + r;
            float4 v = make_float4(0.f, 0.f, 0.f, 0.f);
            if (gr < n) v = *(const float4*)(Hh + (size_t)gr * 128 + k0 + c4);
            xT[c4 + 0][r] = v.x; xT[c4 + 1][r] = v.y;
            xT[c4 + 2][r] = v.z; xT[c4 + 3][r] = v.w;
        }
#pragma unroll
        for (int it = 0; it < 5; it++) {            // stage W2 chunk (32x40)
            int i = tid + it * 256;
            if (i < 1280) {
                int kk = i / 40;
                int c = i - kk * 40;
                wsh[kk][c] = W2[(size_t)(k0 + kk) * 40 + c];
            }
        }
        __syncthreads();
#pragma unroll
        for (int k = 0; k < 32; k++) {
            float a[8];
#pragma unroll
            for (int m = 0; m < 8; m++) a[m] = xT[k][tr + 32 * m];
            float b[5];
#pragma unroll
            for (int c = 0; c < 5; c++) b[c] = wsh[k][tc * 5 + c];
#pragma unroll
            for (int m = 0; m < 8; m++)
#pragma unroll
                for (int c = 0; c < 5; c++) acc[m][c] = fmaf(a[m], b[c], acc[m][c]);
        }
        __syncthreads();
    }
#pragma unroll
    for (int m = 0; m < 8; m++) {
        int gr = row0 + tr + 32 * m;
        if (gr < n) {
#pragma unroll
            for (int c = 0; c < 5; c++)
                H2[(size_t)gr * 40 + tc * 5 + c] = acc[m][c];
        }
    }
}

// ---- edge scatter-aggregation, 128 features, 32 threads/edge, float4 each
__global__ void k_agg128(const float* __restrict__ H, const float* __restrict__ w,
                         const int* __restrict__ src, const int* __restrict__ dst,
                         float* __restrict__ out, int E) {
    int gid = blockIdx.x * blockDim.x + threadIdx.x;
    if (gid >= E * 32) return;
    int j = gid >> 5;
    int c4 = (gid & 31) << 2;
    int s = src[j], d = dst[j];
    float ww = w[j];
    float4 v = *(const float4*)(H + (size_t)s * 128 + c4);
    float* o = out + (size_t)d * 128 + c4;
    atomicAdd(o + 0, v.x * ww);
    atomicAdd(o + 1, v.y * ww);
    atomicAdd(o + 2, v.z * ww);
    atomicAdd(o + 3, v.w * ww);
}

// ---- edge scatter-aggregation, 40 features, 10 threads/edge
__global__ void k_agg40(const float* __restrict__ H2, const float* __restrict__ w,
                        const int* __restrict__ src, const int* __restrict__ dst,
                        float* __restrict__ out, int E) {
    int gid = blockIdx.x * blockDim.x + threadIdx.x;
    if (gid >= E * 10) return;
    int j = gid / 10;
    int cg = gid - j * 10;
    int c4 = cg << 2;
    int s = src[j], d = dst[j];
    float ww = w[j];
    float4 v = *(const float4*)(H2 + (size_t)s * 40 + c4);
    float* o = out + (size_t)d * 40 + c4;
    atomicAdd(o + 0, v.x * ww);
    atomicAdd(o + 1, v.y * ww);
    atomicAdd(o + 2, v.z * ww);
    atomicAdd(o + 3, v.w * ww);
}

// ---- h = relu(A + H*dinv^2 + b1), in place into A
__global__ void k_relu_bias_self(float* __restrict__ A, const float* __restrict__ H,
                                 const float* __restrict__ dinv,
                                 const float* __restrict__ b1, int n) {
    int gid = blockIdx.x * blockDim.x + threadIdx.x;
    if (gid >= n * 32) return;
    int i = gid >> 5;
    int c4 = (gid & 31) << 2;
    float di = dinv[i];
    float sw = di * di;
    float4 a = *(float4*)(A + (size_t)i * 128 + c4);
    float4 h = *(const float4*)(H + (size_t)i * 128 + c4);
    float4 b = *(const float4*)(b1 + c4);
    float4 r;
    r.x = fmaxf(fmaf(h.x, sw, a.x) + b.x, 0.f);
    r.y = fmaxf(fmaf(h.y, sw, a.y) + b.y, 0.f);
    r.z = fmaxf(fmaf(h.z, sw, a.z) + b.z, 0.f);
    r.w = fmaxf(fmaf(h.w, sw, a.w) + b.w, 0.f);
    *(float4*)(A + (size_t)i * 128 + c4) = r;
}

// ---- out += H2*dinv^2 + b2 (self-loop + bias), in place
__global__ void k_final40(float* __restrict__ out, const float* __restrict__ H2,
                          const float* __restrict__ dinv,
                          const float* __restrict__ b2, int n) {
    int gid = blockIdx.x * blockDim.x + threadIdx.x;
    if (gid >= n * 10) return;
    int i = gid / 10;
    int cg = gid - i * 10;
    int c4 = cg << 2;
    float di = dinv[i];
    float sw = di * di;
    float4 o = *(float4*)(out + (size_t)i * 40 + c4);
    float4 h = *(const float4*)(H2 + (size_t)i * 40 + c4);
    float4 b = *(const float4*)(b2 + c4);
    o.x += fmaf(h.x, sw, b.x);
    o.y += fmaf(h.y, sw, b.y);
    o.z += fmaf(h.z, sw, b.z);
    o.w += fmaf(h.w, sw, b.w);
    *(float4*)(out + (size_t)i * 40 + c4) = o;
}

extern "C" void kernel_launch(void* const* d_in, const int* in_sizes, int n_in,
                              void* d_out, int out_size, void* d_ws, size_t ws_size,
                              hipStream_t stream) {
    const float* x  = (const float*)d_in[0];
    const void*  e  = d_in[1];
    const float* W1 = (const float*)d_in[2];
    const float* b1 = (const float*)d_in[3];
    const float* W2 = (const float*)d_in[4];
    const float* b2 = (const float*)d_in[5];
    float* out = (float*)d_out;

    const int n = in_sizes[0] / 128;
    const int E = in_sizes[1] / 2;

    float* ws   = (float*)d_ws;
    float* deg  = ws;                       // n
    float* dinv = deg + n;                  // n
    float* wno  = dinv + n;                 // E
    int*   idx  = (int*)(wno + E);          // 2E
    int*   flag = idx + 2 * E;              // 1
    float* H1   = (float*)(flag + 1);       // n*128
    float* A1   = H1 + (size_t)n * 128;     // n*128
    float* H2   = H1;                       // n*40, reused after relu

    const int* src = idx;
    const int* dst = idx + E;

    // index dtype normalization (int64 vs int32 storage)
    hipMemsetAsync(flag, 0, sizeof(int), stream);
    k_detect<<<1, 256, 0, stream>>>((const int*)e, flag);
    k_convert<<<(2 * E + 255) / 256, 256, 0, stream>>>(e, idx, flag, 2 * E);

    // degree / norm
    hipMemsetAsync(deg, 0, (size_t)n * sizeof(float), stream);
    k_count<<<(E + 255) / 256, 256, 0, stream>>>(dst, deg, E);
    k_dinv<<<(n + 255) / 256, 256, 0, stream>>>(deg, dinv, n);
    k_norm<<<(E + 255) / 256, 256, 0, stream>>>(src, dst, dinv, wno, E);

    // layer 1
    k_gemm1<<<(n + 127) / 128, 256, 0, stream>>>(x, W1, H1, n);
    hipMemsetAsync(A1, 0, (size_t)n * 128 * sizeof(float), stream);
    k_agg128<<<(E * 32 + 255) / 256, 256, 0, stream>>>(H1, wno, src, dst, A1, E);
    k_relu_bias_self<<<(n * 32 + 255) / 256, 256, 0, stream>>>(A1, H1, dinv, b1, n);

    // layer 2
    k_gemm2<<<(n + 255) / 256, 256, 0, stream>>>(A1, W2, H2, n);
    hipMemsetAsync(out, 0, (size_t)n * 40 * sizeof(float), stream);
    k_agg40<<<(E * 10 + 255) / 256, 256, 0, stream>>>(H2, wno, src, dst, out, E);
    k_final40<<<(n * 10 + 255) / 256, 256, 0, stream>>>(out, H2, dinv, b2, n);
}

// Round 2
// 650.050 us; speedup vs baseline: 6.3764x; 6.3764x over previous
//
#include <hip/hip_runtime.h>

// ---------------------------------------------------------------------------
// 2-layer GCN forward, CSR-gather formulation (no float atomics).
// Pipeline: detect idx dtype -> int degree count -> dinv -> prefix scan
// (rowStart) -> scatter edges into CSR (by dst) -> GEMM1 -> wave-per-node
// gather128 (+relu+bias+self fused) -> GEMM2 -> gather40 (+bias+self fused).
// ---------------------------------------------------------------------------

__global__ void k_detect(const int* __restrict__ e32, int* __restrict__ flag) {
    // sample odd int32 slots of first 256 pairs; any nonzero => int32 storage
    int t = threadIdx.x;
    if (e32[2 * t + 1] != 0) atomicOr(flag, 1);
}

__global__ void k_countE(const void* __restrict__ e_raw, const int* __restrict__ flag,
                         int* __restrict__ degI, int E) {
    int j = blockIdx.x * blockDim.x + threadIdx.x;
    if (j >= E) return;
    int d;
    if (*flag == 0) d = (int)((const long long*)e_raw)[E + j];
    else            d = ((const int*)e_raw)[E + j];
    atomicAdd(&degI[d], 1);
}

__global__ void k_dinv(const int* __restrict__ degI, float* __restrict__ dinv, int n) {
    int i = blockIdx.x * blockDim.x + threadIdx.x;
    if (i < n) dinv[i] = rsqrtf((float)degI[i] + 1.0f);   // +1 = self-loop
}

// ---- 3-kernel exclusive prefix scan over degI -> rowStart -------------------
__global__ void k_scan1(const int* __restrict__ deg, int* __restrict__ rs,
                        int* __restrict__ bsum, int n) {
    __shared__ int sh[256];
    int i = blockIdx.x * 256 + threadIdx.x;
    int v = (i < n) ? deg[i] : 0;
    sh[threadIdx.x] = v;
    __syncthreads();
    for (int off = 1; off < 256; off <<= 1) {
        int t = (threadIdx.x >= off) ? sh[threadIdx.x - off] : 0;
        __syncthreads();
        sh[threadIdx.x] += t;
        __syncthreads();
    }
    if (i < n) rs[i] = sh[threadIdx.x] - v;          // exclusive
    if (threadIdx.x == 255) bsum[blockIdx.x] = sh[255];
}

__global__ void k_scan2(int* __restrict__ bsum, int nb) {
    __shared__ int sh[512];
    int t = threadIdx.x;
    int v = (t < nb) ? bsum[t] : 0;
    sh[t] = v;
    __syncthreads();
    for (int off = 1; off < 512; off <<= 1) {
        int u = (t >= off) ? sh[t - off] : 0;
        __syncthreads();
        sh[t] += u;
        __syncthreads();
    }
    if (t < nb) bsum[t] = sh[t] - v;                 // exclusive block offsets
}

__global__ void k_scan3(int* __restrict__ rs, const int* __restrict__ bsum, int n) {
    int i = blockIdx.x * 256 + threadIdx.x;
    if (i < n) rs[i] += bsum[blockIdx.x];
}

__global__ void k_scatter(const void* __restrict__ e_raw, const int* __restrict__ flag,
                          const float* __restrict__ dinv, const int* __restrict__ rs,
                          int* __restrict__ cursor, int* __restrict__ eSrc,
                          float* __restrict__ eW, int E) {
    int j = blockIdx.x * blockDim.x + threadIdx.x;
    if (j >= E) return;
    int s, d;
    if (*flag == 0) {
        s = (int)((const long long*)e_raw)[j];
        d = (int)((const long long*)e_raw)[E + j];
    } else {
        s = ((const int*)e_raw)[j];
        d = ((const int*)e_raw)[E + j];
    }
    float w = dinv[s] * dinv[d];
    int pos = rs[d] + atomicAdd(&cursor[d], 1);
    eSrc[pos] = s;
    eW[pos] = w;
}

// ---- GEMM1: [n,128] @ [128,128] -> [n,128] ---------------------------------
__global__ __launch_bounds__(256) void k_gemm1(const float* __restrict__ X,
                                               const float* __restrict__ W,
                                               float* __restrict__ H, int n) {
    __shared__ float xT[32][130];
    __shared__ float wsh[32][128];
    const int tid = threadIdx.x;
    const int row0 = blockIdx.x * 128;
    const int tr = tid & 15;
    const int tc = tid >> 4;
    float acc[8][8];
#pragma unroll
    for (int m = 0; m < 8; m++)
#pragma unroll
        for (int c = 0; c < 8; c++) acc[m][c] = 0.f;

    for (int k0 = 0; k0 < 128; k0 += 32) {
#pragma unroll
        for (int it = 0; it < 4; it++) {
            int i = tid + it * 256;
            int r = i >> 3;
            int c4 = (i & 7) << 2;
            int gr = row0 + r;
            float4 v = make_float4(0.f, 0.f, 0.f, 0.f);
            if (gr < n) v = *(const float4*)(X + (size_t)gr * 128 + k0 + c4);
            xT[c4 + 0][r] = v.x; xT[c4 + 1][r] = v.y;
            xT[c4 + 2][r] = v.z; xT[c4 + 3][r] = v.w;
        }
#pragma unroll
        for (int it = 0; it < 4; it++) {
            int i = tid + it * 256;
            int kk = i >> 5;
            int c4 = (i & 31) << 2;
            *(float4*)&wsh[kk][c4] = *(const float4*)(W + (size_t)(k0 + kk) * 128 + c4);
        }
        __syncthreads();
#pragma unroll
        for (int k = 0; k < 32; k++) {
            float a[8];
#pragma unroll
            for (int m = 0; m < 8; m++) a[m] = xT[k][tr + 16 * m];
            float4 b0 = *(float4*)&wsh[k][tc * 8];
            float4 b1 = *(float4*)&wsh[k][tc * 8 + 4];
            float b[8] = {b0.x, b0.y, b0.z, b0.w, b1.x, b1.y, b1.z, b1.w};
#pragma unroll
            for (int m = 0; m < 8; m++)
#pragma unroll
                for (int c = 0; c < 8; c++) acc[m][c] = fmaf(a[m], b[c], acc[m][c]);
        }
        __syncthreads();
    }
#pragma unroll
    for (int m = 0; m < 8; m++) {
        int gr = row0 + tr + 16 * m;
        if (gr < n) {
            *(float4*)(H + (size_t)gr * 128 + tc * 8) =
                make_float4(acc[m][0], acc[m][1], acc[m][2], acc[m][3]);
            *(float4*)(H + (size_t)gr * 128 + tc * 8 + 4) =
                make_float4(acc[m][4], acc[m][5], acc[m][6], acc[m][7]);
        }
    }
}

// ---- GEMM2: [n,128] @ [128,40] -> [n,40] -----------------------------------
__global__ __launch_bounds__(256) void k_gemm2(const float* __restrict__ Hh,
                                               const float* __restrict__ W2,
                                               float* __restrict__ H2, int n) {
    __shared__ float xT[32][258];
    __shared__ float wsh[32][40];
    const int tid = threadIdx.x;
    const int row0 = blockIdx.x * 256;
    const int tr = tid & 31;
    const int tc = tid >> 5;
    float acc[8][5];
#pragma unroll
    for (int m = 0; m < 8; m++)
#pragma unroll
        for (int c = 0; c < 5; c++) acc[m][c] = 0.f;

    for (int k0 = 0; k0 < 128; k0 += 32) {
#pragma unroll
        for (int it = 0; it < 8; it++) {
            int i = tid + it * 256;
            int r = i >> 3;
            int c4 = (i & 7) << 2;
            int gr = row0 + r;
            float4 v = make_float4(0.f, 0.f, 0.f, 0.f);
            if (gr < n) v = *(const float4*)(Hh + (size_t)gr * 128 + k0 + c4);
            xT[c4 + 0][r] = v.x; xT[c4 + 1][r] = v.y;
            xT[c4 + 2][r] = v.z; xT[c4 + 3][r] = v.w;
        }
#pragma unroll
        for (int it = 0; it < 5; it++) {
            int i = tid + it * 256;
            if (i < 1280) {
                int kk = i / 40;
                int c = i - kk * 40;
                wsh[kk][c] = W2[(size_t)(k0 + kk) * 40 + c];
            }
        }
        __syncthreads();
#pragma unroll
        for (int k = 0; k < 32; k++) {
            float a[8];
#pragma unroll
            for (int m = 0; m < 8; m++) a[m] = xT[k][tr + 32 * m];
            float b[5];
#pragma unroll
            for (int c = 0; c < 5; c++) b[c] = wsh[k][tc * 5 + c];
#pragma unroll
            for (int m = 0; m < 8; m++)
#pragma unroll
                for (int c = 0; c < 5; c++) acc[m][c] = fmaf(a[m], b[c], acc[m][c]);
        }
        __syncthreads();
    }
#pragma unroll
    for (int m = 0; m < 8; m++) {
        int gr = row0 + tr + 32 * m;
        if (gr < n) {
#pragma unroll
            for (int c = 0; c < 5; c++)
                H2[(size_t)gr * 40 + tc * 5 + c] = acc[m][c];
        }
    }
}

// ---- wave-per-node CSR gather, 128 feats, fused relu+bias+self-loop --------
__global__ __launch_bounds__(256) void k_gather128(
    const float* __restrict__ H, const int* __restrict__ rs,
    const int* __restrict__ degI, const int* __restrict__ eSrc,
    const float* __restrict__ eW, const float* __restrict__ dinv,
    const float* __restrict__ b1, float* __restrict__ out, int n) {
    int wave = threadIdx.x >> 6;
    int lane = threadIdx.x & 63;
    int node = blockIdx.x * 4 + wave;
    if (node >= n) return;          // whole wave exits together
    int start = rs[node];
    int deg = degI[node];
    float2 acc = make_float2(0.f, 0.f);
    for (int base = 0; base < deg; base += 64) {
        int idx = start + base + lane;
        int mS = 0;
        float mW = 0.f;
        if (base + lane < deg) { mS = eSrc[idx]; mW = eW[idx]; }
        int cnt = min(64, deg - base);
        for (int t = 0; t < cnt; t++) {
            int s = __shfl(mS, t);
            float w = __shfl(mW, t);
            float2 v = *(const float2*)(H + (size_t)s * 128 + lane * 2);
            acc.x = fmaf(w, v.x, acc.x);
            acc.y = fmaf(w, v.y, acc.y);
        }
    }
    float di = dinv[node];
    float sw = di * di;
    float2 hv = *(const float2*)(H + (size_t)node * 128 + lane * 2);
    float2 bv = *(const float2*)(b1 + lane * 2);
    float2 r;
    r.x = fmaxf(fmaf(hv.x, sw, acc.x) + bv.x, 0.f);
    r.y = fmaxf(fmaf(hv.y, sw, acc.y) + bv.y, 0.f);
    *(float2*)(out + (size_t)node * 128 + lane * 2) = r;
}

// ---- wave-per-node CSR gather, 40 feats, fused bias+self-loop --------------
__global__ __launch_bounds__(256) void k_gather40(
    const float* __restrict__ H2, const int* __restrict__ rs,
    const int* __restrict__ degI, const int* __restrict__ eSrc,
    const float* __restrict__ eW, const float* __restrict__ dinv,
    const float* __restrict__ b2, float* __restrict__ out, int n) {
    int wave = threadIdx.x >> 6;
    int lane = threadIdx.x & 63;
    int node = blockIdx.x * 4 + wave;
    if (node >= n) return;
    int start = rs[node];
    int deg = degI[node];
    float acc = 0.f;
    for (int base = 0; base < deg; base += 64) {
        int idx = start + base + lane;
        int mS = 0;
        float mW = 0.f;
        if (base + lane < deg) { mS = eSrc[idx]; mW = eW[idx]; }
        int cnt = min(64, deg - base);
        for (int t = 0; t < cnt; t++) {
            int s = __shfl(mS, t);
            float w = __shfl(mW, t);
            if (lane < 40) acc = fmaf(w, H2[(size_t)s * 40 + lane], acc);
        }
    }
    if (lane < 40) {
        float di = dinv[node];
        float sw = di * di;
        out[(size_t)node * 40 + lane] =
            fmaf(H2[(size_t)node * 40 + lane], sw, acc) + b2[lane];
    }
}

extern "C" void kernel_launch(void* const* d_in, const int* in_sizes, int n_in,
                              void* d_out, int out_size, void* d_ws, size_t ws_size,
                              hipStream_t stream) {
    const float* x  = (const float*)d_in[0];
    const void*  e  = d_in[1];
    const float* W1 = (const float*)d_in[2];
    const float* b1 = (const float*)d_in[3];
    const float* W2 = (const float*)d_in[4];
    const float* b2 = (const float*)d_in[5];
    float* out = (float*)d_out;

    const int n = in_sizes[0] / 128;
    const int E = in_sizes[1] / 2;
    const int nb = (n + 255) / 256;        // scan blocks (391 for n=100k)

    // workspace layout
    char* p = (char*)d_ws;
    int*   degI   = (int*)p;              p += (size_t)n * 4;
    int*   rs     = (int*)p;              p += (size_t)n * 4;
    int*   cursor = (int*)p;              p += (size_t)n * 4;
    int*   bsum   = (int*)p;              p += 512 * 4;
    int*   flag   = (int*)p;              p += 4;
    float* dinv   = (float*)p;            p += (size_t)n * 4;
    int*   eSrc   = (int*)p;              p += (size_t)E * 4;
    float* eW     = (float*)p;            p += (size_t)E * 4;
    float* H1     = (float*)p;            p += (size_t)n * 128 * 4;
    float* A1     = (float*)p;            p += (size_t)n * 128 * 4;
    float* H2     = H1;                   // reuse after gather128 consumed H1

    // index dtype detect + degree count
    hipMemsetAsync(flag, 0, 4, stream);
    hipMemsetAsync(degI, 0, (size_t)n * 4, stream);
    hipMemsetAsync(cursor, 0, (size_t)n * 4, stream);
    k_detect<<<1, 256, 0, stream>>>((const int*)e, flag);
    k_countE<<<(E + 255) / 256, 256, 0, stream>>>(e, flag, degI, E);
    k_dinv<<<(n + 255) / 256, 256, 0, stream>>>(degI, dinv, n);

    // rowStart = exclusive scan of degI
    k_scan1<<<nb, 256, 0, stream>>>(degI, rs, bsum, n);
    k_scan2<<<1, 512, 0, stream>>>(bsum, nb);
    k_scan3<<<nb, 256, 0, stream>>>(rs, bsum, n);

    // CSR edge scatter (by dst)
    k_scatter<<<(E + 255) / 256, 256, 0, stream>>>(e, flag, dinv, rs, cursor,
                                                   eSrc, eW, E);

    // layer 1: GEMM then gather (+relu+bias+self fused)
    k_gemm1<<<(n + 127) / 128, 256, 0, stream>>>(x, W1, H1, n);
    k_gather128<<<(n + 3) / 4, 256, 0, stream>>>(H1, rs, degI, eSrc, eW, dinv,
                                                 b1, A1, n);

    // layer 2: GEMM then gather (+bias+self fused)
    k_gemm2<<<(n + 255) / 256, 256, 0, stream>>>(A1, W2, H2, n);
    k_gather40<<<(n + 3) / 4, 256, 0, stream>>>(H2, rs, degI, eSrc, eW, dinv,
                                                b2, out, n);
}

// Round 3
// 521.717 us; speedup vs baseline: 7.9449x; 1.2460x over previous
//
#include <hip/hip_runtime.h>

// ---------------------------------------------------------------------------
// 2-layer GCN forward, CSR-gather, bf16-packed gather operands.
// GEMM math in f32; H1/H2 (edge-gathered arrays) stored as packed bf16x2 so
// each gather row is half the bytes. Edge record = int2{src, w_bits} (one 8B
// load/store). Pipeline: memset -> detect -> countE -> scan1(+dinv) -> scan2
// -> scan3 -> scatter -> gemm1(->bf16) -> gather128(fused relu+bias+self)
// -> gemm2(->bf16) -> gather40(fused bias+self).
// ---------------------------------------------------------------------------

typedef unsigned int u32;
typedef unsigned short u16;

static __device__ inline u16 f2bf(float f) {
    u32 u = __float_as_uint(f);
    return (u16)((u + 0x7FFFu + ((u >> 16) & 1u)) >> 16);   // RNE
}
static __device__ inline u32 pack2(float a, float b) {
    return (u32)f2bf(a) | ((u32)f2bf(b) << 16);
}
static __device__ inline float bflo(u32 u) { return __uint_as_float(u << 16); }
static __device__ inline float bfhi(u32 u) { return __uint_as_float(u & 0xffff0000u); }

__global__ void k_detect(const int* __restrict__ e32, int* __restrict__ flag) {
    // sample odd int32 slots of first 256 pairs; any nonzero => int32 storage
    int t = threadIdx.x;
    if (e32[2 * t + 1] != 0) atomicOr(flag, 1);
}

__global__ void k_countE(const void* __restrict__ e_raw, const int* __restrict__ flag,
                         int* __restrict__ degI, int E) {
    int j = blockIdx.x * blockDim.x + threadIdx.x;
    if (j >= E) return;
    int d;
    if (*flag == 0) d = (int)((const long long*)e_raw)[E + j];
    else            d = ((const int*)e_raw)[E + j];
    atomicAdd(&degI[d], 1);
}

// ---- exclusive scan (3 kernels); scan1 also emits dinv ---------------------
__global__ void k_scan1(const int* __restrict__ deg, int* __restrict__ rs,
                        int* __restrict__ bsum, float* __restrict__ dinv, int n) {
    __shared__ int sh[256];
    int i = blockIdx.x * 256 + threadIdx.x;
    int v = (i < n) ? deg[i] : 0;
    if (i < n) dinv[i] = rsqrtf((float)v + 1.0f);      // +1 self-loop
    sh[threadIdx.x] = v;
    __syncthreads();
    for (int off = 1; off < 256; off <<= 1) {
        int t = (threadIdx.x >= off) ? sh[threadIdx.x - off] : 0;
        __syncthreads();
        sh[threadIdx.x] += t;
        __syncthreads();
    }
    if (i < n) rs[i] = sh[threadIdx.x] - v;            // exclusive
    if (threadIdx.x == 255) bsum[blockIdx.x] = sh[255];
}

__global__ void k_scan2(int* __restrict__ bsum, int nb) {
    __shared__ int sh[512];
    int t = threadIdx.x;
    int v = (t < nb) ? bsum[t] : 0;
    sh[t] = v;
    __syncthreads();
    for (int off = 1; off < 512; off <<= 1) {
        int u = (t >= off) ? sh[t - off] : 0;
        __syncthreads();
        sh[t] += u;
        __syncthreads();
    }
    if (t < nb) bsum[t] = sh[t] - v;
}

__global__ void k_scan3(int* __restrict__ rs, const int* __restrict__ bsum, int n) {
    int i = blockIdx.x * 256 + threadIdx.x;
    if (i < n) rs[i] += bsum[blockIdx.x];
}

__global__ void k_scatter(const void* __restrict__ e_raw, const int* __restrict__ flag,
                          const float* __restrict__ dinv, const int* __restrict__ rs,
                          int* __restrict__ cursor, int2* __restrict__ eRec, int E) {
    int j = blockIdx.x * blockDim.x + threadIdx.x;
    if (j >= E) return;
    int s, d;
    if (*flag == 0) {
        s = (int)((const long long*)e_raw)[j];
        d = (int)((const long long*)e_raw)[E + j];
    } else {
        s = ((const int*)e_raw)[j];
        d = ((const int*)e_raw)[E + j];
    }
    float w = dinv[s] * dinv[d];
    int pos = rs[d] + atomicAdd(&cursor[d], 1);
    eRec[pos] = make_int2(s, __float_as_int(w));
}

// ---- GEMM1: [n,128] @ [128,128] -> bf16x2-packed [n,64] u32 ----------------
__global__ __launch_bounds__(256) void k_gemm1(const float* __restrict__ X,
                                               const float* __restrict__ W,
                                               u32* __restrict__ Hb, int n) {
    __shared__ float xT[32][130];
    __shared__ float wsh[32][128];
    const int tid = threadIdx.x;
    const int row0 = blockIdx.x * 128;
    const int tr = tid & 15;
    const int tc = tid >> 4;
    float acc[8][8];
#pragma unroll
    for (int m = 0; m < 8; m++)
#pragma unroll
        for (int c = 0; c < 8; c++) acc[m][c] = 0.f;

    for (int k0 = 0; k0 < 128; k0 += 32) {
#pragma unroll
        for (int it = 0; it < 4; it++) {
            int i = tid + it * 256;
            int r = i >> 3;
            int c4 = (i & 7) << 2;
            int gr = row0 + r;
            float4 v = make_float4(0.f, 0.f, 0.f, 0.f);
            if (gr < n) v = *(const float4*)(X + (size_t)gr * 128 + k0 + c4);
            xT[c4 + 0][r] = v.x; xT[c4 + 1][r] = v.y;
            xT[c4 + 2][r] = v.z; xT[c4 + 3][r] = v.w;
        }
#pragma unroll
        for (int it = 0; it < 4; it++) {
            int i = tid + it * 256;
            int kk = i >> 5;
            int c4 = (i & 31) << 2;
            *(float4*)&wsh[kk][c4] = *(const float4*)(W + (size_t)(k0 + kk) * 128 + c4);
        }
        __syncthreads();
#pragma unroll
        for (int k = 0; k < 32; k++) {
            float a[8];
#pragma unroll
            for (int m = 0; m < 8; m++) a[m] = xT[k][tr + 16 * m];
            float4 b0 = *(float4*)&wsh[k][tc * 8];
            float4 b1 = *(float4*)&wsh[k][tc * 8 + 4];
            float b[8] = {b0.x, b0.y, b0.z, b0.w, b1.x, b1.y, b1.z, b1.w};
#pragma unroll
            for (int m = 0; m < 8; m++)
#pragma unroll
                for (int c = 0; c < 8; c++) acc[m][c] = fmaf(a[m], b[c], acc[m][c]);
        }
        __syncthreads();
    }
#pragma unroll
    for (int m = 0; m < 8; m++) {
        int gr = row0 + tr + 16 * m;
        if (gr < n) {
            uint4 st;
            st.x = pack2(acc[m][0], acc[m][1]);
            st.y = pack2(acc[m][2], acc[m][3]);
            st.z = pack2(acc[m][4], acc[m][5]);
            st.w = pack2(acc[m][6], acc[m][7]);
            *(uint4*)(Hb + (size_t)gr * 64 + tc * 4) = st;
        }
    }
}

// ---- GEMM2: f32 [n,128] @ [128,40] -> bf16 [n,40] --------------------------
__global__ __launch_bounds__(256) void k_gemm2(const float* __restrict__ Hh,
                                               const float* __restrict__ W2,
                                               u16* __restrict__ H2s, int n) {
    __shared__ float xT[32][258];
    __shared__ float wsh[32][40];
    const int tid = threadIdx.x;
    const int row0 = blockIdx.x * 256;
    const int tr = tid & 31;
    const int tc = tid >> 5;
    float acc[8][5];
#pragma unroll
    for (int m = 0; m < 8; m++)
#pragma unroll
        for (int c = 0; c < 5; c++) acc[m][c] = 0.f;

    for (int k0 = 0; k0 < 128; k0 += 32) {
#pragma unroll
        for (int it = 0; it < 8; it++) {
            int i = tid + it * 256;
            int r = i >> 3;
            int c4 = (i & 7) << 2;
            int gr = row0 + r;
            float4 v = make_float4(0.f, 0.f, 0.f, 0.f);
            if (gr < n) v = *(const float4*)(Hh + (size_t)gr * 128 + k0 + c4);
            xT[c4 + 0][r] = v.x; xT[c4 + 1][r] = v.y;
            xT[c4 + 2][r] = v.z; xT[c4 + 3][r] = v.w;
        }
#pragma unroll
        for (int it = 0; it < 5; it++) {
            int i = tid + it * 256;
            if (i < 1280) {
                int kk = i / 40;
                int c = i - kk * 40;
                wsh[kk][c] = W2[(size_t)(k0 + kk) * 40 + c];
            }
        }
        __syncthreads();
#pragma unroll
        for (int k = 0; k < 32; k++) {
            float a[8];
#pragma unroll
            for (int m = 0; m < 8; m++) a[m] = xT[k][tr + 32 * m];
            float b[5];
#pragma unroll
            for (int c = 0; c < 5; c++) b[c] = wsh[k][tc * 5 + c];
#pragma unroll
            for (int m = 0; m < 8; m++)
#pragma unroll
                for (int c = 0; c < 5; c++) acc[m][c] = fmaf(a[m], b[c], acc[m][c]);
        }
        __syncthreads();
    }
#pragma unroll
    for (int m = 0; m < 8; m++) {
        int gr = row0 + tr + 32 * m;
        if (gr < n) {
#pragma unroll
            for (int c = 0; c < 5; c++)
                H2s[(size_t)gr * 40 + tc * 5 + c] = f2bf(acc[m][c]);
        }
    }
}

// ---- wave-per-node gather, 128 feats (bf16 rows), fused relu+bias+self -----
__global__ __launch_bounds__(256) void k_gather128(
    const u32* __restrict__ Hb, const int* __restrict__ rs,
    const int* __restrict__ degI, const int2* __restrict__ eRec,
    const float* __restrict__ dinv, const float* __restrict__ b1,
    float* __restrict__ out, int n) {
    int wave = threadIdx.x >> 6;
    int lane = threadIdx.x & 63;
    int node = blockIdx.x * 4 + wave;
    if (node >= n) return;
    int start = rs[node];
    int deg = degI[node];
    float ax = 0.f, ay = 0.f;
    for (int base = 0; base < deg; base += 64) {
        int2 rec = make_int2(0, 0);
        if (base + lane < deg) rec = eRec[start + base + lane];
        int cnt = min(64, deg - base);
        int t = 0;
        for (; t + 4 <= cnt; t += 4) {       // 4-way MLP
            int s0 = __shfl(rec.x, t + 0), s1 = __shfl(rec.x, t + 1);
            int s2 = __shfl(rec.x, t + 2), s3 = __shfl(rec.x, t + 3);
            float w0 = __int_as_float(__shfl(rec.y, t + 0));
            float w1 = __int_as_float(__shfl(rec.y, t + 1));
            float w2 = __int_as_float(__shfl(rec.y, t + 2));
            float w3 = __int_as_float(__shfl(rec.y, t + 3));
            u32 u0 = Hb[(size_t)s0 * 64 + lane];
            u32 u1 = Hb[(size_t)s1 * 64 + lane];
            u32 u2 = Hb[(size_t)s2 * 64 + lane];
            u32 u3 = Hb[(size_t)s3 * 64 + lane];
            ax = fmaf(w0, bflo(u0), ax); ay = fmaf(w0, bfhi(u0), ay);
            ax = fmaf(w1, bflo(u1), ax); ay = fmaf(w1, bfhi(u1), ay);
            ax = fmaf(w2, bflo(u2), ax); ay = fmaf(w2, bfhi(u2), ay);
            ax = fmaf(w3, bflo(u3), ax); ay = fmaf(w3, bfhi(u3), ay);
        }
        for (; t < cnt; t++) {
            int s = __shfl(rec.x, t);
            float w = __int_as_float(__shfl(rec.y, t));
            u32 u = Hb[(size_t)s * 64 + lane];
            ax = fmaf(w, bflo(u), ax); ay = fmaf(w, bfhi(u), ay);
        }
    }
    float di = dinv[node];
    float sw = di * di;
    u32 us = Hb[(size_t)node * 64 + lane];
    float2 bv = *(const float2*)(b1 + lane * 2);
    float rx = fmaxf(fmaf(bflo(us), sw, ax) + bv.x, 0.f);
    float ry = fmaxf(fmaf(bfhi(us), sw, ay) + bv.y, 0.f);
    *(float2*)(out + (size_t)node * 128 + lane * 2) = make_float2(rx, ry);
}

// ---- wave-per-node gather, 40 feats (bf16 rows), 3 edges/step, fused epilog -
__global__ __launch_bounds__(256) void k_gather40(
    const u32* __restrict__ H2b, const int* __restrict__ rs,
    const int* __restrict__ degI, const int2* __restrict__ eRec,
    const float* __restrict__ dinv, const float* __restrict__ b2,
    float* __restrict__ out, int n) {
    int wave = threadIdx.x >> 6;
    int lane = threadIdx.x & 63;
    int node = blockIdx.x * 4 + wave;
    if (node >= n) return;
    int start = rs[node];
    int deg = degI[node];
    int g = lane / 20;             // subgroup 0..2 active, 3 idle (lanes 60-63)
    int l = lane - g * 20;         // feature-pair index 0..19
    float ax = 0.f, ay = 0.f;
    for (int base = 0; base < deg; base += 64) {
        int2 rec = make_int2(0, 0);
        if (base + lane < deg) rec = eRec[start + base + lane];
        int cnt = min(64, deg - base);
        for (int t = 0; t < cnt; t += 3) {
            int e = (t + g) & 63;
            int s = __shfl(rec.x, e);
            float w = __int_as_float(__shfl(rec.y, e));
            if (g < 3 && t + g < cnt) {
                u32 u = H2b[(size_t)s * 20 + l];
                ax = fmaf(w, bflo(u), ax);
                ay = fmaf(w, bfhi(u), ay);
            }
        }
    }
    // combine the 3 subgroups' partial sums onto lanes 0..19
    float x1 = __shfl(ax, (lane + 20) & 63), y1 = __shfl(ay, (lane + 20) & 63);
    float x2 = __shfl(ax, (lane + 40) & 63), y2 = __shfl(ay, (lane + 40) & 63);
    if (lane < 20) {
        float di = dinv[node];
        float sw = di * di;
        u32 u = H2b[(size_t)node * 20 + l];
        float2 bv = *(const float2*)(b2 + l * 2);
        float ox = ax + x1 + x2 + fmaf(bflo(u), sw, bv.x);
        float oy = ay + y1 + y2 + fmaf(bfhi(u), sw, bv.y);
        *(float2*)(out + (size_t)node * 40 + l * 2) = make_float2(ox, oy);
    }
}

extern "C" void kernel_launch(void* const* d_in, const int* in_sizes, int n_in,
                              void* d_out, int out_size, void* d_ws, size_t ws_size,
                              hipStream_t stream) {
    const float* x  = (const float*)d_in[0];
    const void*  e  = d_in[1];
    const float* W1 = (const float*)d_in[2];
    const float* b1 = (const float*)d_in[3];
    const float* W2 = (const float*)d_in[4];
    const float* b2 = (const float*)d_in[5];
    float* out = (float*)d_out;

    const int n = in_sizes[0] / 128;
    const int E = in_sizes[1] / 2;
    const int nb = (n + 255) / 256;

    // workspace: [flag, degI(n), cursor(n)] zeroed in one memset, then rest
    int*   flag   = (int*)d_ws;
    int*   degI   = flag + 1;
    int*   cursor = degI + n;
    int*   rs     = cursor + n;
    int*   bsum   = rs + n;                      // 512
    float* dinv   = (float*)(bsum + 512);
    size_t off = (size_t)((char*)(dinv + n) - (char*)d_ws);
    off = (off + 15) & ~(size_t)15;
    int2*  eRec   = (int2*)((char*)d_ws + off);          // E * 8 B
    u32*   H1b    = (u32*)((char*)eRec + (size_t)E * 8); // n*64 u32 (bf16x2)
    float* A1     = (float*)(H1b + (size_t)n * 64);      // n*128 f32
    u16*   H2s    = (u16*)(A1 + (size_t)n * 128);        // n*40 bf16
    u32*   H2b    = (u32*)H2s;

    hipMemsetAsync(flag, 0, (size_t)(2 * n + 1) * 4, stream);
    k_detect<<<1, 256, 0, stream>>>((const int*)e, flag);
    k_countE<<<(E + 255) / 256, 256, 0, stream>>>(e, flag, degI, E);

    k_scan1<<<nb, 256, 0, stream>>>(degI, rs, bsum, dinv, n);
    k_scan2<<<1, 512, 0, stream>>>(bsum, nb);
    k_scan3<<<nb, 256, 0, stream>>>(rs, bsum, n);

    k_scatter<<<(E + 255) / 256, 256, 0, stream>>>(e, flag, dinv, rs, cursor,
                                                   eRec, E);

    k_gemm1<<<(n + 127) / 128, 256, 0, stream>>>(x, W1, H1b, n);
    k_gather128<<<(n + 3) / 4, 256, 0, stream>>>(H1b, rs, degI, eRec, dinv,
                                                 b1, A1, n);

    k_gemm2<<<(n + 255) / 256, 256, 0, stream>>>(A1, W2, H2s, n);
    k_gather40<<<(n + 3) / 4, 256, 0, stream>>>(H2b, rs, degI, eRec, dinv,
                                                b2, out, n);
}

// Round 4
// 412.169 us; speedup vs baseline: 10.0565x; 1.2658x over previous
//
#include <hip/hip_runtime.h>

// ---------------------------------------------------------------------------
// 2-layer GCN forward. CSR gather (no float atomics) + bf16 MFMA GEMMs.
// All edge-gathered arrays (H1, A1, H2) stored packed bf16; GEMM accum f32.
// Pipeline: memset -> prepW(bf16 transposed W1/W2) -> detect -> countE ->
// scan1(+dinv) -> scan2 -> scan3 -> scatter -> gemm1(MFMA) ->
// gather128(fused relu+bias+self, bf16 out) -> gemm2(MFMA) ->
// gather40(fused bias+self).
// ---------------------------------------------------------------------------

typedef unsigned int u32;
typedef unsigned short u16;
typedef __attribute__((ext_vector_type(8))) short short8;
typedef __attribute__((ext_vector_type(4))) float floatx4;

static __device__ inline u16 f2bf(float f) {
    u32 u = __float_as_uint(f);
    return (u16)((u + 0x7FFFu + ((u >> 16) & 1u)) >> 16);   // RNE
}
static __device__ inline u32 pack2(float a, float b) {
    return (u32)f2bf(a) | ((u32)f2bf(b) << 16);
}
static __device__ inline float bflo(u32 u) { return __uint_as_float(u << 16); }
static __device__ inline float bfhi(u32 u) { return __uint_as_float(u & 0xffff0000u); }

__global__ void k_detect(const int* __restrict__ e32, int* __restrict__ flag) {
    // sample odd int32 slots of first 256 pairs; any nonzero => int32 storage
    int t = threadIdx.x;
    if (e32[2 * t + 1] != 0) atomicOr(flag, 1);
}

__global__ void k_countE(const void* __restrict__ e_raw, const int* __restrict__ flag,
                         int* __restrict__ degI, int E) {
    int j = blockIdx.x * blockDim.x + threadIdx.x;
    if (j >= E) return;
    int d;
    if (*flag == 0) d = (int)((const long long*)e_raw)[E + j];
    else            d = ((const int*)e_raw)[E + j];
    atomicAdd(&degI[d], 1);
}

// ---- W1 [128,128] -> WTb [c][k] bf16; W2 [128,40] -> W2Tb [48][128] bf16 ---
__global__ void k_prepW(const float* __restrict__ W1, const float* __restrict__ W2,
                        u16* __restrict__ WTb, u16* __restrict__ W2Tb) {
    int id = blockIdx.x * 256 + threadIdx.x;
    if (id < 16384) {
        int k = id >> 7, c = id & 127;           // W1[k][c]
        WTb[c * 128 + k] = f2bf(W1[id]);
    } else {
        int id2 = id - 16384;
        if (id2 < 6144) {                        // 48 x 128, zero-pad cols 40+
            int c = id2 >> 7, k = id2 & 127;
            W2Tb[id2] = f2bf(c < 40 ? W2[k * 40 + c] : 0.f);
        }
    }
}

// ---- exclusive scan (3 kernels); scan1 also emits dinv ---------------------
__global__ void k_scan1(const int* __restrict__ deg, int* __restrict__ rs,
                        int* __restrict__ bsum, float* __restrict__ dinv, int n) {
    __shared__ int sh[256];
    int i = blockIdx.x * 256 + threadIdx.x;
    int v = (i < n) ? deg[i] : 0;
    if (i < n) dinv[i] = rsqrtf((float)v + 1.0f);      // +1 self-loop
    sh[threadIdx.x] = v;
    __syncthreads();
    for (int off = 1; off < 256; off <<= 1) {
        int t = (threadIdx.x >= off) ? sh[threadIdx.x - off] : 0;
        __syncthreads();
        sh[threadIdx.x] += t;
        __syncthreads();
    }
    if (i < n) rs[i] = sh[threadIdx.x] - v;            // exclusive
    if (threadIdx.x == 255) bsum[blockIdx.x] = sh[255];
}

__global__ void k_scan2(int* __restrict__ bsum, int nb) {
    __shared__ int sh[512];
    int t = threadIdx.x;
    int v = (t < nb) ? bsum[t] : 0;
    sh[t] = v;
    __syncthreads();
    for (int off = 1; off < 512; off <<= 1) {
        int u = (t >= off) ? sh[t - off] : 0;
        __syncthreads();
        sh[t] += u;
        __syncthreads();
    }
    if (t < nb) bsum[t] = sh[t] - v;
}

__global__ void k_scan3(int* __restrict__ rs, const int* __restrict__ bsum, int n) {
    int i = blockIdx.x * 256 + threadIdx.x;
    if (i < n) rs[i] += bsum[blockIdx.x];
}

__global__ void k_scatter(const void* __restrict__ e_raw, const int* __restrict__ flag,
                          const float* __restrict__ dinv, const int* __restrict__ rs,
                          int* __restrict__ cursor, int2* __restrict__ eRec, int E) {
    int j = blockIdx.x * blockDim.x + threadIdx.x;
    if (j >= E) return;
    int s, d;
    if (*flag == 0) {
        s = (int)((const long long*)e_raw)[j];
        d = (int)((const long long*)e_raw)[E + j];
    } else {
        s = ((const int*)e_raw)[j];
        d = ((const int*)e_raw)[E + j];
    }
    float w = dinv[s] * dinv[d];
    int pos = rs[d] + atomicAdd(&cursor[d], 1);
    eRec[pos] = make_int2(s, __float_as_int(w));
}

// ---- GEMM1 (MFMA bf16): X[n,128](f32) @ W1 -> H1s[n,128] bf16 --------------
// block: 64 rows, 4 waves in 2x2 grid; each wave 32 rows x 64 cols; K=128.
__global__ __launch_bounds__(256) void k_gemm1(const float* __restrict__ X,
                                               const u16* __restrict__ WTb,
                                               u16* __restrict__ H1s, int n) {
    __shared__ u32 As[64 * 68];     // [row][k/2], pad 68
    __shared__ u32 Bs[128 * 68];    // [col][k/2]
    const int tid = threadIdx.x;
    const int row0 = blockIdx.x * 64;
#pragma unroll
    for (int it = 0; it < 8; it++) {        // stage X, f32 -> bf16
        int i = tid + it * 256;             // 2048 float4
        int r = i >> 5;
        int c4 = (i & 31) << 2;
        int gr = row0 + r;
        float4 v = make_float4(0.f, 0.f, 0.f, 0.f);
        if (gr < n) v = *(const float4*)(X + (size_t)gr * 128 + c4);
        uint2 p;
        p.x = pack2(v.x, v.y);
        p.y = pack2(v.z, v.w);
        *(uint2*)&As[r * 68 + (c4 >> 1)] = p;
    }
#pragma unroll
    for (int it = 0; it < 8; it++) {        // stage WTb (straight copy)
        int i = tid + it * 256;             // 2048 uint4
        int r = i >> 4;
        int c4 = (i & 15) << 2;
        *(uint4*)&Bs[r * 68 + c4] =
            *(const uint4*)((const u32*)WTb + (size_t)r * 64 + c4);
    }
    __syncthreads();

    const int lane = tid & 63;
    const int wave = tid >> 6;
    const int wr = wave >> 1;
    const int wc = wave & 1;
    const int mrow = lane & 15;
    const int quad = lane >> 4;

    floatx4 acc[2][4] = {};
    for (int k0 = 0; k0 < 128; k0 += 32) {
        int koff = (k0 >> 1) + quad * 4;
        short8 a[2], b[4];
#pragma unroll
        for (int i = 0; i < 2; i++)
            a[i] = *(const short8*)&As[((wr * 2 + i) * 16 + mrow) * 68 + koff];
#pragma unroll
        for (int j = 0; j < 4; j++)
            b[j] = *(const short8*)&Bs[((wc * 4 + j) * 16 + mrow) * 68 + koff];
#pragma unroll
        for (int i = 0; i < 2; i++)
#pragma unroll
            for (int j = 0; j < 4; j++)
                acc[i][j] = __builtin_amdgcn_mfma_f32_16x16x32_bf16(
                    a[i], b[j], acc[i][j], 0, 0, 0);
    }
#pragma unroll
    for (int i = 0; i < 2; i++) {
        int gr0 = row0 + (wr * 2 + i) * 16 + quad * 4;
#pragma unroll
        for (int j = 0; j < 4; j++) {
            int gcol = (wc * 4 + j) * 16 + mrow;
#pragma unroll
            for (int rg = 0; rg < 4; rg++) {
                int grow = gr0 + rg;
                if (grow < n) H1s[(size_t)grow * 128 + gcol] = f2bf(acc[i][j][rg]);
            }
        }
    }
}

// ---- GEMM2 (MFMA bf16): A1b[n,64]u32 @ W2 -> H2s[n,40] bf16 ----------------
// block: 64 rows, wave w = row-tile w, 3 col-tiles (cols 0..47, store <40).
__global__ __launch_bounds__(256) void k_gemm2(const u32* __restrict__ A1b,
                                               const u16* __restrict__ W2Tb,
                                               u16* __restrict__ H2s, int n) {
    __shared__ u32 As[64 * 68];
    __shared__ u32 Bs[48 * 68];
    const int tid = threadIdx.x;
    const int row0 = blockIdx.x * 64;
#pragma unroll
    for (int it = 0; it < 4; it++) {        // stage A1 rows (already bf16)
        int i = tid + it * 256;             // 1024 uint4
        int r = i >> 4;
        int c4 = (i & 15) << 2;
        int gr = row0 + r;
        uint4 v = make_uint4(0u, 0u, 0u, 0u);
        if (gr < n) v = *(const uint4*)(A1b + (size_t)gr * 64 + c4);
        *(uint4*)&As[r * 68 + c4] = v;
    }
#pragma unroll
    for (int it = 0; it < 3; it++) {        // stage W2Tb
        int i = tid + it * 256;             // 768 uint4
        int r = i >> 4;
        int c4 = (i & 15) << 2;
        *(uint4*)&Bs[r * 68 + c4] =
            *(const uint4*)((const u32*)W2Tb + (size_t)r * 64 + c4);
    }
    __syncthreads();

    const int lane = tid & 63;
    const int wave = tid >> 6;
    const int mrow = lane & 15;
    const int quad = lane >> 4;

    floatx4 acc[3] = {};
    for (int k0 = 0; k0 < 128; k0 += 32) {
        int koff = (k0 >> 1) + quad * 4;
        short8 a = *(const short8*)&As[(wave * 16 + mrow) * 68 + koff];
#pragma unroll
        for (int j = 0; j < 3; j++) {
            short8 b = *(const short8*)&Bs[(j * 16 + mrow) * 68 + koff];
            acc[j] = __builtin_amdgcn_mfma_f32_16x16x32_bf16(a, b, acc[j], 0, 0, 0);
        }
    }
#pragma unroll
    for (int j = 0; j < 3; j++) {
        int gcol = j * 16 + mrow;
        if (gcol < 40) {
#pragma unroll
            for (int rg = 0; rg < 4; rg++) {
                int grow = row0 + wave * 16 + quad * 4 + rg;
                if (grow < n) H2s[(size_t)grow * 40 + gcol] = f2bf(acc[j][rg]);
            }
        }
    }
}

// ---- wave-per-node gather, 128 feats (bf16 rows), fused relu+bias+self -----
// output packed bf16x2 (A1b) for gemm2
__global__ __launch_bounds__(256) void k_gather128(
    const u32* __restrict__ Hb, const int* __restrict__ rs,
    const int* __restrict__ degI, const int2* __restrict__ eRec,
    const float* __restrict__ dinv, const float* __restrict__ b1,
    u32* __restrict__ outb, int n) {
    int wave = threadIdx.x >> 6;
    int lane = threadIdx.x & 63;
    int node = blockIdx.x * 4 + wave;
    if (node >= n) return;
    int start = rs[node];
    int deg = degI[node];
    float ax = 0.f, ay = 0.f;
    for (int base = 0; base < deg; base += 64) {
        int2 rec = make_int2(0, 0);
        if (base + lane < deg) rec = eRec[start + base + lane];
        int cnt = min(64, deg - base);
        int t = 0;
        for (; t + 4 <= cnt; t += 4) {       // 4-way MLP
            int s0 = __shfl(rec.x, t + 0), s1 = __shfl(rec.x, t + 1);
            int s2 = __shfl(rec.x, t + 2), s3 = __shfl(rec.x, t + 3);
            float w0 = __int_as_float(__shfl(rec.y, t + 0));
            float w1 = __int_as_float(__shfl(rec.y, t + 1));
            float w2 = __int_as_float(__shfl(rec.y, t + 2));
            float w3 = __int_as_float(__shfl(rec.y, t + 3));
            u32 u0 = Hb[(size_t)s0 * 64 + lane];
            u32 u1 = Hb[(size_t)s1 * 64 + lane];
            u32 u2 = Hb[(size_t)s2 * 64 + lane];
            u32 u3 = Hb[(size_t)s3 * 64 + lane];
            ax = fmaf(w0, bflo(u0), ax); ay = fmaf(w0, bfhi(u0), ay);
            ax = fmaf(w1, bflo(u1), ax); ay = fmaf(w1, bfhi(u1), ay);
            ax = fmaf(w2, bflo(u2), ax); ay = fmaf(w2, bfhi(u2), ay);
            ax = fmaf(w3, bflo(u3), ax); ay = fmaf(w3, bfhi(u3), ay);
        }
        for (; t < cnt; t++) {
            int s = __shfl(rec.x, t);
            float w = __int_as_float(__shfl(rec.y, t));
            u32 u = Hb[(size_t)s * 64 + lane];
            ax = fmaf(w, bflo(u), ax); ay = fmaf(w, bfhi(u), ay);
        }
    }
    float di = dinv[node];
    float sw = di * di;
    u32 us = Hb[(size_t)node * 64 + lane];
    float2 bv = *(const float2*)(b1 + lane * 2);
    float rx = fmaxf(fmaf(bflo(us), sw, ax) + bv.x, 0.f);
    float ry = fmaxf(fmaf(bfhi(us), sw, ay) + bv.y, 0.f);
    outb[(size_t)node * 64 + lane] = pack2(rx, ry);
}

// ---- wave-per-node gather, 40 feats (bf16 rows), 3 edges/step, fused epilog -
__global__ __launch_bounds__(256) void k_gather40(
    const u32* __restrict__ H2b, const int* __restrict__ rs,
    const int* __restrict__ degI, const int2* __restrict__ eRec,
    const float* __restrict__ dinv, const float* __restrict__ b2,
    float* __restrict__ out, int n) {
    int wave = threadIdx.x >> 6;
    int lane = threadIdx.x & 63;
    int node = blockIdx.x * 4 + wave;
    if (node >= n) return;
    int start = rs[node];
    int deg = degI[node];
    int g = lane / 20;             // subgroup 0..2 active, 3 idle (lanes 60-63)
    int l = lane - g * 20;         // feature-pair index 0..19
    float ax = 0.f, ay = 0.f;
    for (int base = 0; base < deg; base += 64) {
        int2 rec = make_int2(0, 0);
        if (base + lane < deg) rec = eRec[start + base + lane];
        int cnt = min(64, deg - base);
        for (int t = 0; t < cnt; t += 3) {
            int e = (t + g) & 63;
            int s = __shfl(rec.x, e);
            float w = __int_as_float(__shfl(rec.y, e));
            if (g < 3 && t + g < cnt) {
                u32 u = H2b[(size_t)s * 20 + l];
                ax = fmaf(w, bflo(u), ax);
                ay = fmaf(w, bfhi(u), ay);
            }
        }
    }
    float x1 = __shfl(ax, (lane + 20) & 63), y1 = __shfl(ay, (lane + 20) & 63);
    float x2 = __shfl(ax, (lane + 40) & 63), y2 = __shfl(ay, (lane + 40) & 63);
    if (lane < 20) {
        float di = dinv[node];
        float sw = di * di;
        u32 u = H2b[(size_t)node * 20 + l];
        float2 bv = *(const float2*)(b2 + l * 2);
        float ox = ax + x1 + x2 + fmaf(bflo(u), sw, bv.x);
        float oy = ay + y1 + y2 + fmaf(bfhi(u), sw, bv.y);
        *(float2*)(out + (size_t)node * 40 + l * 2) = make_float2(ox, oy);
    }
}

extern "C" void kernel_launch(void* const* d_in, const int* in_sizes, int n_in,
                              void* d_out, int out_size, void* d_ws, size_t ws_size,
                              hipStream_t stream) {
    const float* x  = (const float*)d_in[0];
    const void*  e  = d_in[1];
    const float* W1 = (const float*)d_in[2];
    const float* b1 = (const float*)d_in[3];
    const float* W2 = (const float*)d_in[4];
    const float* b2 = (const float*)d_in[5];
    float* out = (float*)d_out;

    const int n = in_sizes[0] / 128;
    const int E = in_sizes[1] / 2;
    const int nb = (n + 255) / 256;

    // workspace: [flag, degI(n), cursor(n)] zeroed in one memset, then rest
    int*   flag   = (int*)d_ws;
    int*   degI   = flag + 1;
    int*   cursor = degI + n;
    int*   rs     = cursor + n;
    int*   bsum   = rs + n;                          // 512
    float* dinv   = (float*)(bsum + 512);
    size_t off = (size_t)((char*)(dinv + n) - (char*)d_ws);
    off = (off + 15) & ~(size_t)15;
    u16*   WTb    = (u16*)((char*)d_ws + off);       // 128*128 bf16 (W1^T)
    u16*   W2Tb   = WTb + 16384;                     // 48*128 bf16 (W2^T pad)
    off = (size_t)((char*)(W2Tb + 6144) - (char*)d_ws);
    off = (off + 15) & ~(size_t)15;
    int2*  eRec   = (int2*)((char*)d_ws + off);      // E * 8 B
    u16*   H1s    = (u16*)(eRec + (size_t)E);        // n*128 bf16
    u32*   H1b    = (u32*)H1s;                       // same memory, [n,64] u32
    u32*   A1b    = (u32*)(H1s + (size_t)n * 128);   // n*64 u32 (bf16x2)
    u16*   H2s    = (u16*)(A1b + (size_t)n * 64);    // n*40 bf16
    u32*   H2b    = (u32*)H2s;

    hipMemsetAsync(flag, 0, (size_t)(2 * n + 1) * 4, stream);
    k_prepW<<<88, 256, 0, stream>>>(W1, W2, WTb, W2Tb);
    k_detect<<<1, 256, 0, stream>>>((const int*)e, flag);
    k_countE<<<(E + 255) / 256, 256, 0, stream>>>(e, flag, degI, E);

    k_scan1<<<nb, 256, 0, stream>>>(degI, rs, bsum, dinv, n);
    k_scan2<<<1, 512, 0, stream>>>(bsum, nb);
    k_scan3<<<nb, 256, 0, stream>>>(rs, bsum, n);

    k_scatter<<<(E + 255) / 256, 256, 0, stream>>>(e, flag, dinv, rs, cursor,
                                                   eRec, E);

    k_gemm1<<<(n + 63) / 64, 256, 0, stream>>>(x, WTb, H1s, n);
    k_gather128<<<(n + 3) / 4, 256, 0, stream>>>(H1b, rs, degI, eRec, dinv,
                                                 b1, A1b, n);

    k_gemm2<<<(n + 63) / 64, 256, 0, stream>>>(A1b, W2Tb, H2s, n);
    k_gather40<<<(n + 3) / 4, 256, 0, stream>>>(H2b, rs, degI, eRec, dinv,
                                                b2, out, n);
}